// Round 1
// baseline (2674.472 us; speedup 1.0000x reference)
//
#include <hip/hip_runtime.h>

#define BATCH 256
#define SEQ   2048
#define ISZ   64
#define HID   128
#define GATES 512   // 4*HID
#define KV    192   // ISZ + HID

// One block per batch element. 512 threads:
//   thread t -> half = t>>8 (k-slice), p = t&255 -> gate columns c0=2p, c1=2p+1
// Per step:
//   A: threads<64 write prefetched x_t into LDS v[0:64]; prefetch next x_t
//   B: each thread: partial dot over its 96-long k-slice for its 2 columns
//   C: each thread t combines the two partials of column t, adds bias,
//      applies the per-gate pointwise transform (i raw, f->log_sigmoid,
//      o->sigmoid, z->tanh)
//   D: threads<128 (hidden owner j): stabilized state update, h -> LDS + out
__global__ __launch_bounds__(512, 2) void slstm_kernel(
    const float* __restrict__ x, const float* __restrict__ W,
    const float* __restrict__ R, const float* __restrict__ bias,
    float* __restrict__ out)
{
    __shared__ __align__(16) float v[KV];          // [x_t | h]
    __shared__ __align__(16) float partial[2 * GATES];
    __shared__ __align__(16) float gv[GATES];

    const int t    = threadIdx.x;
    const int half = t >> 8;        // 0 or 1 (wave-uniform)
    const int p    = t & 255;
    const int c0   = 2 * p;
    const int c1   = c0 + 1;

    // ---- preload weights into registers: k = half*96 + kk over [x|h] ----
    float w0[96], w1[96];
#pragma unroll
    for (int kk = 0; kk < 96; ++kk) {
        const int k = half * 96 + kk;
        const float* s0 = (k < ISZ) ? (W + c0 * ISZ + k) : (R + (k - ISZ) * GATES + c0);
        const float* s1 = (k < ISZ) ? (W + c1 * ISZ + k) : (R + (k - ISZ) * GATES + c1);
        w0[kk] = *s0;
        w1[kk] = *s1;
    }
    const float bb = bias[t];

    // ---- init state ----
    float c_st = 0.f, n_st = 0.f, m_st = 0.f;
    if (t < HID) v[ISZ + t] = 0.f;

    const float* xb   = x   + (size_t)blockIdx.x * SEQ * ISZ;
    float*       outb = out + (size_t)blockIdx.x * SEQ * HID;

    float xreg = (t < ISZ) ? xb[t] : 0.f;   // prefetch for s=0

    for (int s = 0; s < SEQ; ++s) {
        // ---- stage A: publish x_t, prefetch x_{t+1} ----
        if (t < ISZ) {
            v[t] = xreg;
            xreg = (s + 1 < SEQ) ? xb[(s + 1) * ISZ + t] : 0.f;
        }
        __syncthreads();

        // ---- stage B: partial dots ----
        float acc0 = 0.f, acc1 = 0.f;
        const float4* v4 = (const float4*)(v + half * 96);
#pragma unroll
        for (int kk = 0; kk < 24; ++kk) {
            const float4 ch = v4[kk];
            acc0 = fmaf(ch.x, w0[4 * kk + 0], acc0);
            acc1 = fmaf(ch.x, w1[4 * kk + 0], acc1);
            acc0 = fmaf(ch.y, w0[4 * kk + 1], acc0);
            acc1 = fmaf(ch.y, w1[4 * kk + 1], acc1);
            acc0 = fmaf(ch.z, w0[4 * kk + 2], acc0);
            acc1 = fmaf(ch.z, w1[4 * kk + 2], acc1);
            acc0 = fmaf(ch.w, w0[4 * kk + 3], acc0);
            acc1 = fmaf(ch.w, w1[4 * kk + 3], acc1);
        }
        ((float2*)(partial + half * GATES))[p] = make_float2(acc0, acc1);
        __syncthreads();

        // ---- stage C: combine + per-gate pointwise (wave-uniform branch) ----
        {
            const float g    = partial[t] + partial[GATES + t] + bb;
            const int   type = t >> 7;     // 0:i 1:f 2:o 3:z, uniform per wave
            float r;
            if (type == 0) {
                r = g;                                   // i_tilda (raw)
            } else if (type == 1) {
                // log_sigmoid(g) = -softplus(-g), stabilized
                const float y  = -g;
                const float sp = (y > 15.f) ? y : __logf(1.f + __expf(y));
                r = -sp;
            } else if (type == 2) {
                r = 1.f / (1.f + __expf(-g));            // sigmoid(o)
            } else {
                const float e = __expf(2.f * g);         // tanh(z)
                r = 1.f - 2.f / (e + 1.f);
            }
            gv[t] = r;
        }
        __syncthreads();

        // ---- stage D: state update (owner thread j = t < 128) ----
        if (t < HID) {
            const float it = gv[t];
            const float lf = gv[HID + t];
            const float so = gv[2 * HID + t];
            const float tz = gv[3 * HID + t];

            const float m_new = fmaxf(lf + m_st, it);
            const float ip    = __expf(it - m_new);
            const float fp    = __expf(lf + m_st - m_new);
            c_st = fp * c_st + ip * tz;
            n_st = fp * n_st + ip;
            m_st = m_new;

            const float ratio = c_st / n_st;
            const float e     = __expf(2.f * ratio);
            const float th    = 1.f - 2.f / (e + 1.f);
            const float h     = so * th;

            v[ISZ + t]     = h;     // feed next step
            outb[s * HID + t] = h;  // coalesced 128-float store
        }
        // no barrier needed here: stage-A writes (v[0:64]) are disjoint from
        // stage-D writes (v[64:192]); the loop-top __syncthreads() orders
        // both against the next stage-B reads.
    }
}

extern "C" void kernel_launch(void* const* d_in, const int* in_sizes, int n_in,
                              void* d_out, int out_size, void* d_ws, size_t ws_size,
                              hipStream_t stream) {
    const float* x = (const float*)d_in[0];
    const float* W = (const float*)d_in[1];
    const float* R = (const float*)d_in[2];
    const float* b = (const float*)d_in[3];
    float* out = (float*)d_out;

    slstm_kernel<<<dim3(BATCH), dim3(512), 0, stream>>>(x, W, R, b, out);
}

// Round 2
// 2431.966 us; speedup vs baseline: 1.0997x; 1.0997x over previous
//
#include <hip/hip_runtime.h>
#include <hip/hip_fp16.h>

#define BATCH 256
#define SEQ   2048
#define ISZ   64
#define HID   128
#define GATES 512   // 4*HID
#define KV    192   // ISZ + HID
#define NPART 8     // k-parts == waves
#define KSL   24    // KV / NPART  (k-slice per thread)
#define NCOL  8     // columns per thread

typedef _Float16 half2v __attribute__((ext_vector_type(2)));

#if __has_builtin(__builtin_amdgcn_fdot2)
#define FDOT2(a, b, c) __builtin_amdgcn_fdot2((a), (b), (c), false)
#else
static __device__ __forceinline__ float fdot2_fb(half2v a, half2v b, float c) {
    c = fmaf((float)a[0], (float)b[0], c);
    c = fmaf((float)a[1], (float)b[1], c);
    return c;
}
#define FDOT2(a, b, c) fdot2_fb((a), (b), (c))
#endif

// One block per batch element, 512 threads (8 waves).
// wave w = k-part (slice [w*24, w*24+24) of v=[x|h], f16 in LDS).
// lane l owns columns l*8 .. l*8+7. Weights: 96 packed-half2 VGPRs/thread.
// Per step: B) 96 x v_dot2_f32_f16 -> 8 partials, float4-pair write
//           C) threads<256: combine 8 parts for 2 cols + gate transform
//           D) threads<128: stabilized state update, h -> LDS(f16) + out
__global__ __launch_bounds__(512, 2) void slstm_kernel(
    const float* __restrict__ x, const float* __restrict__ W,
    const float* __restrict__ R, const float* __restrict__ bias,
    float* __restrict__ out)
{
    __shared__ __align__(16) __half vh[KV];             // [x_t | h] in f16
    __shared__ __align__(16) float  partial[NPART * GATES];  // 16 KB
    __shared__ __align__(16) float  gv[GATES];

    const int t    = threadIdx.x;
    const int w    = t >> 6;    // wave id == k-part (wave-uniform)
    const int lane = t & 63;

    // ---- preload weights: cols lane*8+i, k = w*24+kk, packed half2 ----
    half2v wh[NCOL][KSL / 2];
#pragma unroll
    for (int i = 0; i < NCOL; ++i) {
        const int c = lane * NCOL + i;
#pragma unroll
        for (int kk = 0; kk < KSL; kk += 2) {
            const int k0 = w * KSL + kk;       // always even; W/R split at 64 never splits a pair
            const int k1 = k0 + 1;
            const float f0 = (k0 < ISZ) ? W[c * ISZ + k0] : R[(k0 - ISZ) * GATES + c];
            const float f1 = (k1 < ISZ) ? W[c * ISZ + k1] : R[(k1 - ISZ) * GATES + c];
            half2v hv;
            hv[0] = (_Float16)f0;
            hv[1] = (_Float16)f1;
            wh[i][kk / 2] = hv;
        }
    }

    // bias for stage C (thread t<256 owns cols 2t, 2t+1)
    float bb0 = 0.f, bb1 = 0.f;
    if (t < 256) {
        const float2 bv = ((const float2*)bias)[t];
        bb0 = bv.x; bb1 = bv.y;
    }

    // state (owner t < 128)
    float c_st = 0.f, n_st = 0.f, m_st = 0.f;
    if (t < HID) vh[ISZ + t] = __half(0.0f);

    const float* xb   = x   + (size_t)blockIdx.x * SEQ * ISZ;
    float*       outb = out + (size_t)blockIdx.x * SEQ * HID;

    float xreg = 0.f;
    if (t < ISZ) {
        vh[t] = __half(xb[t]);      // x_0
        xreg  = xb[ISZ + t];        // prefetch x_1
    }

    for (int s = 0; s < SEQ; ++s) {
        __syncthreads();   // sync1: x_s / h_{s-1} visible in vh

        // ---- stage B: 96 dot2 over this wave's 24-element f16 slice ----
        const uint4* vp = (const uint4*)((const char*)vh + w * (KSL * 2)); // 48 B offset, 16B-aligned
        const uint4 c0 = vp[0], c1 = vp[1], c2 = vp[2];
        uint32_t vv[12];
        vv[0] = c0.x; vv[1]  = c0.y; vv[2]  = c0.z; vv[3]  = c0.w;
        vv[4] = c1.x; vv[5]  = c1.y; vv[6]  = c1.z; vv[7]  = c1.w;
        vv[8] = c2.x; vv[9]  = c2.y; vv[10] = c2.z; vv[11] = c2.w;

        float acc[NCOL] = {0.f, 0.f, 0.f, 0.f, 0.f, 0.f, 0.f, 0.f};
#pragma unroll
        for (int kk = 0; kk < 12; ++kk) {
            const half2v hv = __builtin_bit_cast(half2v, vv[kk]);
#pragma unroll
            for (int i = 0; i < NCOL; ++i)
                acc[i] = FDOT2(hv, wh[i][kk], acc[i]);
        }
        {   // contiguous per-wave write: partial[w*512 + lane*8 .. +7]
            float4* pw = (float4*)(partial + w * GATES + lane * NCOL);
            pw[0] = make_float4(acc[0], acc[1], acc[2], acc[3]);
            pw[1] = make_float4(acc[4], acc[5], acc[6], acc[7]);
        }
        __syncthreads();   // sync2: partials visible

        // ---- stage C: combine + per-gate pointwise (wave-uniform type) ----
        if (t < 256) {
            float g0 = bb0, g1 = bb1;
#pragma unroll
            for (int p = 0; p < NPART; ++p) {
                const float2 pv = ((const float2*)partial)[p * 256 + t];
                g0 += pv.x; g1 += pv.y;
            }
            const int type = t >> 6;   // cols 2t,2t+1 share gate; uniform per wave
            float r0, r1;
            if (type == 0) {                       // i: raw
                r0 = g0; r1 = g1;
            } else if (type == 1) {                // f: log_sigmoid = -softplus(-g)
                const float y0 = -g0, y1 = -g1;
                r0 = -((y0 > 15.f) ? y0 : __logf(1.f + __expf(y0)));
                r1 = -((y1 > 15.f) ? y1 : __logf(1.f + __expf(y1)));
            } else if (type == 2) {                // o: sigmoid
                r0 = __builtin_amdgcn_rcpf(1.f + __expf(-g0));
                r1 = __builtin_amdgcn_rcpf(1.f + __expf(-g1));
            } else {                               // z: tanh
                const float e0 = __expf(2.f * g0);
                const float e1 = __expf(2.f * g1);
                r0 = 1.f - 2.f * __builtin_amdgcn_rcpf(e0 + 1.f);
                r1 = 1.f - 2.f * __builtin_amdgcn_rcpf(e1 + 1.f);
            }
            ((float2*)gv)[t] = make_float2(r0, r1);
        }
        __syncthreads();   // sync3: gv visible

        // ---- stage D: state update (owner j = t < 128) ----
        if (t < HID) {
            const float it = gv[t];
            const float lf = gv[HID + t];
            const float so = gv[2 * HID + t];
            const float tz = gv[3 * HID + t];

            const float m_new = fmaxf(lf + m_st, it);
            const float ip    = __expf(it - m_new);
            const float fp    = __expf(lf + m_st - m_new);
            c_st = fp * c_st + ip * tz;
            n_st = fp * n_st + ip;
            m_st = m_new;

            const float ratio = c_st * __builtin_amdgcn_rcpf(n_st);
            const float e     = __expf(2.f * ratio);
            const float h     = so * (1.f - 2.f * __builtin_amdgcn_rcpf(e + 1.f));

            vh[ISZ + t]       = __half(h);   // feed next step (f16)
            outb[s * HID + t] = h;           // coalesced f32 store
        }
        // publish x_{s+1}, prefetch x_{s+2} (disjoint LDS region from h)
        if (t < ISZ) {
            vh[t] = __half(xreg);
            xreg  = (s + 2 < SEQ) ? xb[(s + 2) * ISZ + t] : 0.f;
        }
    }
}

extern "C" void kernel_launch(void* const* d_in, const int* in_sizes, int n_in,
                              void* d_out, int out_size, void* d_ws, size_t ws_size,
                              hipStream_t stream) {
    const float* x = (const float*)d_in[0];
    const float* W = (const float*)d_in[1];
    const float* R = (const float*)d_in[2];
    const float* b = (const float*)d_in[3];
    float* out = (float*)d_out;

    slstm_kernel<<<dim3(BATCH), dim3(512), 0, stream>>>(x, W, R, b, out);
}